// Round 2
// baseline (17176.027 us; speedup 1.0000x reference)
//
#include <hip/hip_runtime.h>

#define SEQL 512
#define BATCH 256
#define EMB 256
#define HID 512
#define NTOT 2048  // 4*HID

typedef __attribute__((ext_vector_type(8))) short bf16x8;
typedef __attribute__((ext_vector_type(4))) float f32x4;
typedef unsigned short u16;

// ---------- helpers ----------
static __device__ __forceinline__ u16 f2bf(float f) {
  unsigned u = __float_as_uint(f);
  u += 0x7FFFu + ((u >> 16) & 1u);  // RNE
  return (u16)(u >> 16);
}
static __device__ __forceinline__ float bf2f(u16 s) {
  return __uint_as_float(((unsigned)s) << 16);
}
static __device__ __forceinline__ float sigmoidf_(float z) {
  return 1.f / (1.f + __expf(-z));
}
static __device__ __forceinline__ float tanhf_(float x) {
  float e = __expf(2.f * fabsf(x));
  float t = 1.f - 2.f / (e + 1.f);
  return copysignf(t, x);
}
static __device__ __forceinline__ f32x4 mfma16(bf16x8 a, bf16x8 b, f32x4 c) {
  return __builtin_amdgcn_mfma_f32_16x16x32_bf16(a, b, c, 0, 0, 0);
}
static __device__ __forceinline__ void gld16(const u16* g, u16* l) {
  __builtin_amdgcn_global_load_lds((const __attribute__((address_space(1))) void*)g,
                                   (__attribute__((address_space(3))) void*)l, 16, 0, 0);
}

// ---------- split f32 -> bf16 hi/lo ----------
__global__ void k_split(const float* __restrict__ src, u16* __restrict__ hi,
                        u16* __restrict__ lo, int n) {
  for (int i = blockIdx.x * blockDim.x + threadIdx.x; i < n;
       i += gridDim.x * blockDim.x) {
    float v = src[i];
    u16 h = f2bf(v);
    hi[i] = h;
    lo[i] = f2bf(v - bf2f(h));
  }
}

// bias2[n] : n = g*512+j ; 2*b for f,i,o ; 1*b for a
__global__ void k_bias2(const float* __restrict__ bf_, const float* __restrict__ bi_,
                        const float* __restrict__ bo_, const float* __restrict__ ba_,
                        float* __restrict__ bias2) {
  int n = blockIdx.x * blockDim.x + threadIdx.x;
  if (n >= NTOT) return;
  int g = n >> 9, j = n & 511;
  const float* p = (g == 0) ? bf_ : (g == 1) ? bi_ : (g == 2) ? bo_ : ba_;
  bias2[n] = ((g < 3) ? 2.f : 1.f) * p[j];
}

// ---------- chunk GEMM: G2 tiles = Xc[Mc][256] @ Wcat[2048][256]^T + bias2
// split-bf16: C = Ahi*Bhi + Ahi*Blo + Alo*Bhi.
// G2 tile layout per (tloc, bgrp(16), j16(32)): [g(4)][bq(4)][j15(16)][r(4)] f32
//   b = bgrp*16 + bq*4 + r ; gatecol n = g*512 + j16*16 + j15
__global__ __launch_bounds__(256) void k_gemm(
    const u16* __restrict__ Ahi, const u16* __restrict__ Alo,
    const u16* __restrict__ Bhi, const u16* __restrict__ Blo,
    const float* __restrict__ bias2, float* __restrict__ G2) {
  __shared__ u16 lds[4][128 * 64];
  const int tid = threadIdx.x;
  const int lane = tid & 63;
  const int w = tid >> 6;
  const int wm = (w >> 1) * 64, wn = (w & 1) * 64;
  const int m0 = blockIdx.y * 128, n0 = blockIdx.x * 128;
  const int l15 = lane & 15, lhi = lane >> 4;

  f32x4 acc[4][4] = {};

  for (int k0 = 0; k0 < EMB; k0 += 64) {
    __syncthreads();
    for (int c = 0; c < 4; ++c) {
      int idx = tid + c * 256;          // 0..1023
      int row = idx >> 3;               // 0..127
      int col = (idx & 7) * 8;          // 0..56
      long ga = (long)(m0 + row) * EMB + k0 + col;
      long gb = (long)(n0 + row) * EMB + k0 + col;
      gld16(Ahi + ga, &lds[0][idx * 8]);
      gld16(Alo + ga, &lds[1][idx * 8]);
      gld16(Bhi + gb, &lds[2][idx * 8]);
      gld16(Blo + gb, &lds[3][idx * 8]);
    }
    __syncthreads();
#pragma unroll
    for (int ks = 0; ks < 2; ++ks) {
      int ko = ks * 32 + lhi * 8;
      bf16x8 ah[4], al[4], bh[4], bl[4];
#pragma unroll
      for (int f = 0; f < 4; ++f) {
        int ra = (wm + f * 16 + l15) * 64 + ko;
        int rb = (wn + f * 16 + l15) * 64 + ko;
        ah[f] = *(const bf16x8*)&lds[0][ra];
        al[f] = *(const bf16x8*)&lds[1][ra];
        bh[f] = *(const bf16x8*)&lds[2][rb];
        bl[f] = *(const bf16x8*)&lds[3][rb];
      }
#pragma unroll
      for (int i = 0; i < 4; ++i)
#pragma unroll
        for (int j = 0; j < 4; ++j) {
          acc[i][j] = mfma16(ah[i], bh[j], acc[i][j]);
          acc[i][j] = mfma16(ah[i], bl[j], acc[i][j]);
          acc[i][j] = mfma16(al[i], bh[j], acc[i][j]);
        }
    }
  }
  // epilogue -> permuted G2 tiles, one dwordx4 store per acc vector
#pragma unroll
  for (int j = 0; j < 4; ++j) {
    int n = n0 + wn + j * 16 + l15;
    float bv = bias2[n];
    int g = n >> 9, jj = n & 511;
    int j16 = jj >> 4, j15 = jj & 15;
#pragma unroll
    for (int i = 0; i < 4; ++i) {
      int mb = m0 + wm + i * 16 + lhi * 4;
      int tloc = mb >> 8, brow = mb & 255;
      int bgrp = brow >> 4, bq = (brow >> 2) & 3;
      f32x4 v = acc[i][j];
      v[0] += bv; v[1] += bv; v[2] += bv; v[3] += bv;
      size_t addr = ((((size_t)(tloc * 16 + bgrp) * 32 + j16) * 4 + g) * 4 + bq) * 64 +
                    (size_t)j15 * 4;
      *(f32x4*)&G2[addr] = v;
    }
  }
}

// ---------- persistent recurrence, group-barrier (16 blocks / batch-slice) ----------
// 256 blocks x 256 thr. grp=bslice (16 b rows), mem=j-slice (32 cols).
// Group members share bid&15 -> same XCD under bid%8 mapping.
__global__ __launch_bounds__(256, 1) void k_rnn(
    const u16* __restrict__ WaaHi, const u16* __restrict__ WaaLo,
    const float* __restrict__ G2,
    u16* __restrict__ h0hi, u16* __restrict__ h0lo,
    u16* __restrict__ h1hi, u16* __restrict__ h1lo,
    float* __restrict__ cSave, unsigned* __restrict__ flags,
    float* __restrict__ out, int t0, int nsteps) {
  const int tid = threadIdx.x;
  const int lane = tid & 63;
  const int w = tid >> 6;
  const int jsub = w >> 1, ksub = w & 1;
  const int l15 = lane & 15, lhi = lane >> 4;
  const int bid = blockIdx.x;
  const int grp = ((bid & 7) << 1) | ((bid >> 3) & 1);  // 0..15
  const int mem = bid >> 4;                             // 0..15
  const int b0 = grp * 16;
  const int j0 = mem * 32 + jsub * 16;
  const int j16 = mem * 2 + jsub;
  const bool owner = (ksub == 0);

  __shared__ float red[2][64][4];

  // persistent Waa B-fragments
  bf16x8 wh[8], wl[8];
  {
    long base = (long)(j0 + l15) * HID + ksub * 256 + lhi * 8;
#pragma unroll
    for (int s = 0; s < 8; ++s) {
      wh[s] = *(const bf16x8*)&WaaHi[base + s * 32];
      wl[s] = *(const bf16x8*)&WaaLo[base + s * 32];
    }
  }

  f32x4 c = {0.f, 0.f, 0.f, 0.f};
  const long cbase = (long)(b0 + lhi * 4) * HID + j0 + l15;
  if (owner && t0 > 0) {
#pragma unroll
    for (int r = 0; r < 4; ++r) c[r] = cSave[cbase + (long)r * HID];
  }

  const long abase = (long)(b0 + l15) * HID + ksub * 256 + lhi * 8;
  unsigned* flag = &flags[grp * 32];

  float gv[4][4];
  if (owner) {
    size_t tb = ((size_t)(0 * 16 + grp) * 32 + j16) * 1024;
#pragma unroll
    for (int g = 0; g < 4; ++g) {
      f32x4 v = *(const f32x4*)&G2[tb + (size_t)(g * 4 + lhi) * 64 + (size_t)l15 * 4];
#pragma unroll
      for (int r = 0; r < 4; ++r) gv[g][r] = v[r];
    }
  }

  for (int tl = 0; tl < nsteps; ++tl) {
    const int gt = t0 + tl;
    const u16* hHi = (gt & 1) ? h1hi : h0hi;
    const u16* hLo = (gt & 1) ? h1lo : h0lo;
    u16* nHi = (gt & 1) ? h0hi : h1hi;
    u16* nLo = (gt & 1) ? h0lo : h1lo;

    bf16x8 ah[8], al[8];
#pragma unroll
    for (int s = 0; s < 8; ++s) {
      ah[s] = *(const bf16x8*)&hHi[abase + s * 32];
      al[s] = *(const bf16x8*)&hLo[abase + s * 32];
    }

    f32x4 a0 = {0.f, 0.f, 0.f, 0.f}, a1 = a0, a2 = a0;
#pragma unroll
    for (int s = 0; s < 8; ++s) {
      a0 = mfma16(ah[s], wh[s], a0);
      a1 = mfma16(ah[s], wl[s], a1);
      a2 = mfma16(al[s], wh[s], a2);
    }
    f32x4 acc = (a0 + a1) + a2;

    if (ksub == 1) *(f32x4*)&red[jsub][lane][0] = acc;

    // prefetch next step's preactivations (independent of h)
    float gvn[4][4];
    if (owner && tl + 1 < nsteps) {
      size_t tb = ((size_t)((tl + 1) * 16 + grp) * 32 + j16) * 1024;
#pragma unroll
      for (int g = 0; g < 4; ++g) {
        f32x4 v = *(const f32x4*)&G2[tb + (size_t)(g * 4 + lhi) * 64 + (size_t)l15 * 4];
#pragma unroll
        for (int r = 0; r < 4; ++r) gvn[g][r] = v[r];
      }
    }

    __syncthreads();
    if (owner) {
      f32x4 p = *(const f32x4*)&red[jsub][lane][0];
      acc += p;
#pragma unroll
      for (int r = 0; r < 4; ++r) {
        float z = acc[r];
        float ft = sigmoidf_(gv[0][r] + z);
        float it = sigmoidf_(gv[1][r] + z);
        float ot = sigmoidf_(gv[2][r] + z);
        float cp = tanhf_(gv[3][r] + z);
        c[r] = ft * c[r] + it * cp;
        float h = ot * tanhf_(c[r]);
        int b = b0 + lhi * 4 + r;
        int jj = j0 + l15;
        if (gt == SEQL - 1) {
          out[(long)b * HID + jj] = h;
        } else {
          u16 hh = f2bf(h);
          nHi[(long)b * HID + jj] = hh;
          nLo[(long)b * HID + jj] = f2bf(h - bf2f(hh));
        }
      }
      if (tl + 1 < nsteps) {
#pragma unroll
        for (int g = 0; g < 4; ++g)
#pragma unroll
          for (int r = 0; r < 4; ++r) gv[g][r] = gvn[g][r];
      }
    }

    if (tl + 1 < nsteps) {
      __threadfence();
      __syncthreads();
      if (tid == 0) {
        __hip_atomic_fetch_add(flag, 1u, __ATOMIC_RELEASE, __HIP_MEMORY_SCOPE_AGENT);
        unsigned tgt = 16u * (unsigned)(tl + 1);
        long guard = 0;
        while (__hip_atomic_load(flag, __ATOMIC_ACQUIRE, __HIP_MEMORY_SCOPE_AGENT) < tgt) {
          __builtin_amdgcn_s_sleep(1);
          if (++guard > (1L << 26)) break;  // bounded: fail visibly, never hang
        }
      }
      __syncthreads();
    }
  }

  if (owner && t0 + nsteps < SEQL) {
#pragma unroll
    for (int r = 0; r < 4; ++r) cSave[cbase + (long)r * HID] = c[r];
  }
}

// ---------- host ----------
extern "C" void kernel_launch(void* const* d_in, const int* in_sizes, int n_in,
                              void* d_out, int out_size, void* d_ws, size_t ws_size,
                              hipStream_t stream) {
  const float* X   = (const float*)d_in[0];
  const float* Wfx = (const float*)d_in[1];
  const float* Wix = (const float*)d_in[2];
  const float* Wox = (const float*)d_in[3];
  const float* Wax = (const float*)d_in[4];
  const float* Waa = (const float*)d_in[5];
  const float* bfp = (const float*)d_in[6];
  const float* bip = (const float*)d_in[7];
  const float* bop = (const float*)d_in[8];
  const float* bap = (const float*)d_in[9];
  float* out = (float*)d_out;

  char* ws = (char*)d_ws;
  size_t off = 0;
  auto take = [&](size_t n) {
    void* p = ws + off;
    off += (n + 255) & ~(size_t)255;
    return p;
  };
  u16* WxHi  = (u16*)take((size_t)NTOT * EMB * 2);   // 1 MB
  u16* WxLo  = (u16*)take((size_t)NTOT * EMB * 2);
  u16* WaaHi = (u16*)take((size_t)HID * HID * 2);    // 512 KB
  u16* WaaLo = (u16*)take((size_t)HID * HID * 2);
  float* bias2 = (float*)take((size_t)NTOT * 4);
  u16* h0hi = (u16*)take((size_t)BATCH * HID * 2);   // keep h0hi,h0lo adjacent
  u16* h0lo = (u16*)take((size_t)BATCH * HID * 2);
  u16* h1hi = (u16*)take((size_t)BATCH * HID * 2);
  u16* h1lo = (u16*)take((size_t)BATCH * HID * 2);
  float* cSave = (float*)take((size_t)BATCH * HID * 4);
  unsigned* flags = (unsigned*)take(16 * 32 * 4);
  size_t fixed_end = off;

  // per-step: Xsplit 256KB + G2 2MB
  const size_t perstep = (size_t)BATCH * EMB * 2 * 2 + (size_t)BATCH * NTOT * 4;
  int C = 0;
  const int cands[] = {512, 256, 128, 64, 32, 16, 8, 4, 2, 1};
  for (int cand : cands)
    if (fixed_end + (size_t)cand * perstep <= ws_size) { C = cand; break; }
  if (C == 0) return;  // workspace too small to operate at all

  u16* XcHi = (u16*)take((size_t)C * BATCH * EMB * 2);
  u16* XcLo = (u16*)take((size_t)C * BATCH * EMB * 2);
  float* G2 = (float*)take((size_t)C * BATCH * NTOT * 4);

  // one-time prep
  const float* wx[4] = {Wfx, Wix, Wox, Wax};
  for (int g = 0; g < 4; ++g)
    k_split<<<256, 256, 0, stream>>>(wx[g], WxHi + (size_t)g * HID * EMB,
                                     WxLo + (size_t)g * HID * EMB, HID * EMB);
  k_split<<<512, 256, 0, stream>>>(Waa, WaaHi, WaaLo, HID * HID);
  k_bias2<<<8, 256, 0, stream>>>(bfp, bip, bop, bap, bias2);
  hipMemsetAsync(h0hi, 0, (size_t)BATCH * HID * 2 * 2, stream);  // h0 hi+lo = 0

  const int nch = SEQL / C;
  for (int ch = 0; ch < nch; ++ch) {
    int t0 = ch * C;
    hipMemsetAsync(flags, 0, 16 * 32 * 4, stream);
    k_split<<<2048, 256, 0, stream>>>(X + (size_t)t0 * BATCH * EMB, XcHi, XcLo,
                                      C * BATCH * EMB);
    dim3 gg(NTOT / 128, C * 2);
    k_gemm<<<gg, 256, 0, stream>>>(XcHi, XcLo, WxHi, WxLo, bias2, G2);
    k_rnn<<<256, 256, 0, stream>>>(WaaHi, WaaLo, G2, h0hi, h0lo, h1hi, h1lo,
                                   cSave, flags, out, t0, C);
  }
}

// Round 3
// 3806.805 us; speedup vs baseline: 4.5119x; 4.5119x over previous
//
#include <hip/hip_runtime.h>

#define SEQL 512
#define BATCH 256
#define EMB 256
#define HID 512
#define NTOT 2048  // 4*HID

typedef __attribute__((ext_vector_type(8))) short bf16x8;
typedef __attribute__((ext_vector_type(4))) float f32x4;
typedef unsigned short u16;

// ---------- helpers ----------
static __device__ __forceinline__ u16 f2bf(float f) {
  unsigned u = __float_as_uint(f);
  u += 0x7FFFu + ((u >> 16) & 1u);  // RNE
  return (u16)(u >> 16);
}
static __device__ __forceinline__ float bf2f(u16 s) {
  return __uint_as_float(((unsigned)s) << 16);
}
static __device__ __forceinline__ float sigmoidf_(float z) {
  return 1.f / (1.f + __expf(-z));
}
static __device__ __forceinline__ float tanhf_(float x) {
  float e = __expf(2.f * fabsf(x));
  float t = 1.f - 2.f / (e + 1.f);
  return copysignf(t, x);
}
static __device__ __forceinline__ f32x4 mfma16(bf16x8 a, bf16x8 b, f32x4 c) {
  return __builtin_amdgcn_mfma_f32_16x16x32_bf16(a, b, c, 0, 0, 0);
}
static __device__ __forceinline__ void gld16(const u16* g, u16* l) {
  __builtin_amdgcn_global_load_lds((const __attribute__((address_space(1))) void*)g,
                                   (__attribute__((address_space(3))) void*)l, 16, 0, 0);
}
// device-scope (MALL, coherent across XCDs) 16B load — no cache maintenance
static __device__ __forceinline__ bf16x8 ldx4_dev(const u16* p) {
  bf16x8 r;
  asm volatile("global_load_dwordx4 %0, %1, off sc1" : "=v"(r) : "v"(p));
  return r;
}
// device-scope 2B store (write-through to MALL)
static __device__ __forceinline__ void st2_dev(u16* p, unsigned v) {
  asm volatile("global_store_short %0, %1, off sc1" :: "v"(p), "v"(v) : "memory");
}

// ---------- split f32 -> bf16 hi/lo ----------
__global__ void k_split(const float* __restrict__ src, u16* __restrict__ hi,
                        u16* __restrict__ lo, int n) {
  for (int i = blockIdx.x * blockDim.x + threadIdx.x; i < n;
       i += gridDim.x * blockDim.x) {
    float v = src[i];
    u16 h = f2bf(v);
    hi[i] = h;
    lo[i] = f2bf(v - bf2f(h));
  }
}

// bias2[n] : n = g*512+j ; 2*b for f,i,o ; 1*b for a
__global__ void k_bias2(const float* __restrict__ bf_, const float* __restrict__ bi_,
                        const float* __restrict__ bo_, const float* __restrict__ ba_,
                        float* __restrict__ bias2) {
  int n = blockIdx.x * blockDim.x + threadIdx.x;
  if (n >= NTOT) return;
  int g = n >> 9, j = n & 511;
  const float* p = (g == 0) ? bf_ : (g == 1) ? bi_ : (g == 2) ? bo_ : ba_;
  bias2[n] = ((g < 3) ? 2.f : 1.f) * p[j];
}

// ---------- chunk GEMM: G2 tiles = Xc[Mc][256] @ Wcat[2048][256]^T + bias2
__global__ __launch_bounds__(256) void k_gemm(
    const u16* __restrict__ Ahi, const u16* __restrict__ Alo,
    const u16* __restrict__ Bhi, const u16* __restrict__ Blo,
    const float* __restrict__ bias2, float* __restrict__ G2) {
  __shared__ u16 lds[4][128 * 64];
  const int tid = threadIdx.x;
  const int lane = tid & 63;
  const int w = tid >> 6;
  const int wm = (w >> 1) * 64, wn = (w & 1) * 64;
  const int m0 = blockIdx.y * 128, n0 = blockIdx.x * 128;
  const int l15 = lane & 15, lhi = lane >> 4;

  f32x4 acc[4][4] = {};

  for (int k0 = 0; k0 < EMB; k0 += 64) {
    __syncthreads();
    for (int c = 0; c < 4; ++c) {
      int idx = tid + c * 256;
      int row = idx >> 3;
      int col = (idx & 7) * 8;
      long ga = (long)(m0 + row) * EMB + k0 + col;
      long gb = (long)(n0 + row) * EMB + k0 + col;
      gld16(Ahi + ga, &lds[0][idx * 8]);
      gld16(Alo + ga, &lds[1][idx * 8]);
      gld16(Bhi + gb, &lds[2][idx * 8]);
      gld16(Blo + gb, &lds[3][idx * 8]);
    }
    __syncthreads();
#pragma unroll
    for (int ks = 0; ks < 2; ++ks) {
      int ko = ks * 32 + lhi * 8;
      bf16x8 ah[4], al[4], bh[4], bl[4];
#pragma unroll
      for (int f = 0; f < 4; ++f) {
        int ra = (wm + f * 16 + l15) * 64 + ko;
        int rb = (wn + f * 16 + l15) * 64 + ko;
        ah[f] = *(const bf16x8*)&lds[0][ra];
        al[f] = *(const bf16x8*)&lds[1][ra];
        bh[f] = *(const bf16x8*)&lds[2][rb];
        bl[f] = *(const bf16x8*)&lds[3][rb];
      }
#pragma unroll
      for (int i = 0; i < 4; ++i)
#pragma unroll
        for (int j = 0; j < 4; ++j) {
          acc[i][j] = mfma16(ah[i], bh[j], acc[i][j]);
          acc[i][j] = mfma16(ah[i], bl[j], acc[i][j]);
          acc[i][j] = mfma16(al[i], bh[j], acc[i][j]);
        }
    }
  }
#pragma unroll
  for (int j = 0; j < 4; ++j) {
    int n = n0 + wn + j * 16 + l15;
    float bv = bias2[n];
    int g = n >> 9, jj = n & 511;
    int j16 = jj >> 4, j15 = jj & 15;
#pragma unroll
    for (int i = 0; i < 4; ++i) {
      int mb = m0 + wm + i * 16 + lhi * 4;
      int tloc = mb >> 8, brow = mb & 255;
      int bgrp = brow >> 4, bq = (brow >> 2) & 3;
      f32x4 v = acc[i][j];
      v[0] += bv; v[1] += bv; v[2] += bv; v[3] += bv;
      size_t addr = ((((size_t)(tloc * 16 + bgrp) * 32 + j16) * 4 + g) * 4 + bq) * 64 +
                    (size_t)j15 * 4;
      *(f32x4*)&G2[addr] = v;
    }
  }
}

// ---------- persistent recurrence, MALL-based group barrier ----------
__global__ __launch_bounds__(256, 1) void k_rnn(
    const u16* __restrict__ WaaHi, const u16* __restrict__ WaaLo,
    const float* __restrict__ G2,
    u16* __restrict__ h0hi, u16* __restrict__ h0lo,
    u16* __restrict__ h1hi, u16* __restrict__ h1lo,
    float* __restrict__ cSave, unsigned* __restrict__ flags,
    float* __restrict__ out, int t0, int nsteps) {
  const int tid = threadIdx.x;
  const int lane = tid & 63;
  const int w = tid >> 6;
  const int jsub = w >> 1, ksub = w & 1;
  const int l15 = lane & 15, lhi = lane >> 4;
  const int bid = blockIdx.x;
  const int grp = ((bid & 7) << 1) | ((bid >> 3) & 1);  // 0..15
  const int mem = bid >> 4;                             // 0..15
  const int b0 = grp * 16;
  const int j0 = mem * 32 + jsub * 16;
  const int j16 = mem * 2 + jsub;
  const bool owner = (ksub == 0);

  __shared__ float red[2][64][4];

  // persistent Waa B-fragments, pinned in VGPRs (opaque asm stops remat)
  bf16x8 wh[8], wl[8];
  {
    long base = (long)(j0 + l15) * HID + ksub * 256 + lhi * 8;
#pragma unroll
    for (int s = 0; s < 8; ++s) {
      wh[s] = *(const bf16x8*)&WaaHi[base + s * 32];
      wl[s] = *(const bf16x8*)&WaaLo[base + s * 32];
    }
#pragma unroll
    for (int s = 0; s < 8; ++s) {
      asm volatile("" : "+v"(wh[s]));
      asm volatile("" : "+v"(wl[s]));
    }
  }

  f32x4 c = {0.f, 0.f, 0.f, 0.f};
  const long cbase = (long)(b0 + lhi * 4) * HID + j0 + l15;
  if (owner && t0 > 0) {
#pragma unroll
    for (int r = 0; r < 4; ++r) c[r] = cSave[cbase + (long)r * HID];
  }

  const long abase = (long)(b0 + l15) * HID + ksub * 256 + lhi * 8;
  unsigned* flag = &flags[grp * 32];

  float gv[4][4];
  if (owner) {
    size_t tb = ((size_t)(0 * 16 + grp) * 32 + j16) * 1024;
#pragma unroll
    for (int g = 0; g < 4; ++g) {
      f32x4 v = *(const f32x4*)&G2[tb + (size_t)(g * 4 + lhi) * 64 + (size_t)l15 * 4];
#pragma unroll
      for (int r = 0; r < 4; ++r) gv[g][r] = v[r];
    }
  }

  for (int tl = 0; tl < nsteps; ++tl) {
    const int gt = t0 + tl;
    const u16* hHi = (gt & 1) ? h1hi : h0hi;
    const u16* hLo = (gt & 1) ? h1lo : h0lo;
    u16* nHi = (gt & 1) ? h0hi : h1hi;
    u16* nLo = (gt & 1) ? h0lo : h1lo;

    // A-fragments (h) from MALL (device-coherent), no cache maintenance
    bf16x8 ah[8], al[8];
#pragma unroll
    for (int s = 0; s < 8; ++s) {
      ah[s] = ldx4_dev(hHi + abase + s * 32);
      al[s] = ldx4_dev(hLo + abase + s * 32);
    }
    asm volatile("s_waitcnt vmcnt(0)" ::: "memory");
    __builtin_amdgcn_sched_barrier(0);

    f32x4 a0 = {0.f, 0.f, 0.f, 0.f}, a1 = a0, a2 = a0;
#pragma unroll
    for (int s = 0; s < 8; ++s) {
      a0 = mfma16(ah[s], wh[s], a0);
      a1 = mfma16(ah[s], wl[s], a1);
      a2 = mfma16(al[s], wh[s], a2);
    }
    f32x4 acc = (a0 + a1) + a2;

    if (ksub == 1) *(f32x4*)&red[jsub][lane][0] = acc;

    // prefetch next step's preactivations (normal cached loads)
    float gvn[4][4];
    if (owner && tl + 1 < nsteps) {
      size_t tb = ((size_t)((tl + 1) * 16 + grp) * 32 + j16) * 1024;
#pragma unroll
      for (int g = 0; g < 4; ++g) {
        f32x4 v = *(const f32x4*)&G2[tb + (size_t)(g * 4 + lhi) * 64 + (size_t)l15 * 4];
#pragma unroll
        for (int r = 0; r < 4; ++r) gvn[g][r] = v[r];
      }
    }

    __syncthreads();
    if (owner) {
      f32x4 p = *(const f32x4*)&red[jsub][lane][0];
      acc += p;
#pragma unroll
      for (int r = 0; r < 4; ++r) {
        float z = acc[r];
        float ft = sigmoidf_(gv[0][r] + z);
        float it = sigmoidf_(gv[1][r] + z);
        float ot = sigmoidf_(gv[2][r] + z);
        float cp = tanhf_(gv[3][r] + z);
        c[r] = ft * c[r] + it * cp;
        float h = ot * tanhf_(c[r]);
        int b = b0 + lhi * 4 + r;
        int jj = j0 + l15;
        if (gt == SEQL - 1) {
          out[(long)b * HID + jj] = h;
        } else {
          u16 hh = f2bf(h);
          st2_dev(&nHi[(long)b * HID + jj], (unsigned)hh);
          st2_dev(&nLo[(long)b * HID + jj], (unsigned)f2bf(h - bf2f(hh)));
        }
      }
      if (tl + 1 < nsteps) {
#pragma unroll
        for (int g = 0; g < 4; ++g)
#pragma unroll
          for (int r = 0; r < 4; ++r) gv[g][r] = gvn[g][r];
      }
    }

    if (tl + 1 < nsteps) {
      // release: per-wave drain of sc1 stores, then raw device-scope add
      asm volatile("s_waitcnt vmcnt(0)" ::: "memory");
      if ((tid & 127) == 0) {  // lane0 of each owner wave (tid 0 and 128)
        unsigned one = 1u;
        asm volatile("global_atomic_add %0, %1, off sc1" :: "v"(flag), "v"(one)
                     : "memory");
      }
      if (tid == 0) {  // spin on MALL with plain sc-flagged loads (no L2 inv!)
        unsigned tgt = 32u * (unsigned)(tl + 1);
        long guard = 0;
        unsigned v;
        for (;;) {
          asm volatile("global_load_dword %0, %1, off sc0 sc1\n\ts_waitcnt vmcnt(0)"
                       : "=v"(v) : "v"(flag) : "memory");
          if (v >= tgt) break;
          __builtin_amdgcn_s_sleep(1);
          if (++guard > (1L << 22)) break;  // bounded: fail visibly, never hang
        }
      }
      __syncthreads();
    }
  }

  if (owner && t0 + nsteps < SEQL) {
#pragma unroll
    for (int r = 0; r < 4; ++r) cSave[cbase + (long)r * HID] = c[r];
  }
}

// ---------- host ----------
extern "C" void kernel_launch(void* const* d_in, const int* in_sizes, int n_in,
                              void* d_out, int out_size, void* d_ws, size_t ws_size,
                              hipStream_t stream) {
  const float* X   = (const float*)d_in[0];
  const float* Wfx = (const float*)d_in[1];
  const float* Wix = (const float*)d_in[2];
  const float* Wox = (const float*)d_in[3];
  const float* Wax = (const float*)d_in[4];
  const float* Waa = (const float*)d_in[5];
  const float* bfp = (const float*)d_in[6];
  const float* bip = (const float*)d_in[7];
  const float* bop = (const float*)d_in[8];
  const float* bap = (const float*)d_in[9];
  float* out = (float*)d_out;

  char* ws = (char*)d_ws;
  size_t off = 0;
  auto take = [&](size_t n) {
    void* p = ws + off;
    off += (n + 255) & ~(size_t)255;
    return p;
  };
  u16* WxHi  = (u16*)take((size_t)NTOT * EMB * 2);
  u16* WxLo  = (u16*)take((size_t)NTOT * EMB * 2);
  u16* WaaHi = (u16*)take((size_t)HID * HID * 2);
  u16* WaaLo = (u16*)take((size_t)HID * HID * 2);
  float* bias2 = (float*)take((size_t)NTOT * 4);
  u16* h0hi = (u16*)take((size_t)BATCH * HID * 2);
  u16* h0lo = (u16*)take((size_t)BATCH * HID * 2);
  u16* h1hi = (u16*)take((size_t)BATCH * HID * 2);
  u16* h1lo = (u16*)take((size_t)BATCH * HID * 2);
  float* cSave = (float*)take((size_t)BATCH * HID * 4);
  unsigned* flags = (unsigned*)take(16 * 32 * 4);
  size_t fixed_end = off;

  const size_t perstep = (size_t)BATCH * EMB * 2 * 2 + (size_t)BATCH * NTOT * 4;
  int C = 0;
  const int cands[] = {512, 256, 128, 64, 32, 16, 8, 4, 2, 1};
  for (int cand : cands)
    if (fixed_end + (size_t)cand * perstep <= ws_size) { C = cand; break; }
  if (C == 0) return;

  u16* XcHi = (u16*)take((size_t)C * BATCH * EMB * 2);
  u16* XcLo = (u16*)take((size_t)C * BATCH * EMB * 2);
  float* G2 = (float*)take((size_t)C * BATCH * NTOT * 4);

  const float* wx[4] = {Wfx, Wix, Wox, Wax};
  for (int g = 0; g < 4; ++g)
    k_split<<<256, 256, 0, stream>>>(wx[g], WxHi + (size_t)g * HID * EMB,
                                     WxLo + (size_t)g * HID * EMB, HID * EMB);
  k_split<<<512, 256, 0, stream>>>(Waa, WaaHi, WaaLo, HID * HID);
  k_bias2<<<8, 256, 0, stream>>>(bfp, bip, bop, bap, bias2);
  hipMemsetAsync(h0hi, 0, (size_t)BATCH * HID * 2 * 2, stream);

  const int nch = SEQL / C;
  for (int ch = 0; ch < nch; ++ch) {
    int t0 = ch * C;
    hipMemsetAsync(flags, 0, 16 * 32 * 4, stream);
    k_split<<<2048, 256, 0, stream>>>(X + (size_t)t0 * BATCH * EMB, XcHi, XcLo,
                                      C * BATCH * EMB);
    dim3 gg(NTOT / 128, C * 2);
    k_gemm<<<gg, 256, 0, stream>>>(XcHi, XcLo, WxHi, WxLo, bias2, G2);
    k_rnn<<<256, 256, 0, stream>>>(WaaHi, WaaLo, G2, h0hi, h0lo, h1hi, h1lo,
                                   cSave, flags, out, t0, C);
  }
}